// Round 4
// baseline (3144.929 us; speedup 1.0000x reference)
//
#include <hip/hip_runtime.h>

// ---------------------------------------------------------------------------
// TransformerBlock: B=2, L=2048, D=2048, H=16, HD=128, FF=8192.
// Dual-dtype (runtime-detected): pipelines instantiated for DT=0 (f32 I/O)
// and DT=1 (bf16 I/O); a detector kernel writes a flag; each kernel no-ops
// unless flag==PID. Intermediates are always bf16.
// Workspace (64MB + flag word):
//   qkv: [0,48)   (dead after attn)
//   x2 : [0,16)   (after qkv dead; in-place updated by FF partial)
//   h2 : [16,32)
//   a  : [32,64)  (FF activation chunk, 4096 cols, reused 2x)
//   h  : [48,64)  (dead after qkv gemm)  /  o: [48,64) (after h dead)
//   flag: at min(64MB, ws_size-4)
// ---------------------------------------------------------------------------

typedef __attribute__((ext_vector_type(8))) short bf16x8;
typedef __attribute__((ext_vector_type(4))) float f32x4;

__device__ __forceinline__ float b2f(unsigned short u) {
    return __uint_as_float(((unsigned int)u) << 16);
}
__device__ __forceinline__ unsigned short f2b(float f) {
    unsigned int i = __float_as_uint(f);
    i += 0x7fffu + ((i >> 16) & 1u);   // RNE
    return (unsigned short)(i >> 16);
}

// ---- typed I/O helpers: DT=1 bf16, DT=0 f32 -------------------------------
template<int DT> struct IO;
template<> struct IO<1> {
    static __device__ __forceinline__ void load8(const void* p, size_t i, float* o) {
        uint4 v = *(const uint4*)((const unsigned short*)p + i);
        const unsigned short* u = (const unsigned short*)&v;
#pragma unroll
        for (int e = 0; e < 8; e++) o[e] = b2f(u[e]);
    }
    static __device__ __forceinline__ float load1(const void* p, size_t i) {
        return b2f(((const unsigned short*)p)[i]);
    }
    static __device__ __forceinline__ void store1(void* p, size_t i, float v) {
        ((unsigned short*)p)[i] = f2b(v);
    }
};
template<> struct IO<0> {
    static __device__ __forceinline__ void load8(const void* p, size_t i, float* o) {
        float4 a = *(const float4*)((const float*)p + i);
        float4 b = *(const float4*)((const float*)p + i + 4);
        o[0]=a.x; o[1]=a.y; o[2]=a.z; o[3]=a.w;
        o[4]=b.x; o[5]=b.y; o[6]=b.z; o[7]=b.w;
    }
    static __device__ __forceinline__ float load1(const void* p, size_t i) {
        return ((const float*)p)[i];
    }
    static __device__ __forceinline__ void store1(void* p, size_t i, float v) {
        ((float*)p)[i] = v;
    }
};

// ---------------------------------------------------------------------------
// Detector: classify x's encoding. For each 32-bit word, the LOW ushort is a
// real bf16 value (exponent ~[100,140]) iff data is bf16; for f32 data it is
// mantissa junk (uniform exponent, ~16% in range). flag = 1 (bf16) / 0 (f32).
// ---------------------------------------------------------------------------
__global__ __launch_bounds__(256) void detect_kernel(
    const unsigned int* __restrict__ x, int* __restrict__ flag)
{
    const int t = threadIdx.x;
    int cnt = 0;
    for (int i = t; i < 2048; i += 256) {
        unsigned int e = (x[i] >> 7) & 0xFFu;
        cnt += (e >= 100u && e <= 140u) ? 1 : 0;
    }
#pragma unroll
    for (int off = 32; off; off >>= 1) cnt += __shfl_xor(cnt, off);
    __shared__ int red[4];
    if ((t & 63) == 0) red[t >> 6] = cnt;
    __syncthreads();
    if (t == 0) {
        int tot = red[0] + red[1] + red[2] + red[3];
        flag[0] = (2 * tot > 2048) ? 1 : 0;
    }
}

// ---------------------------------------------------------------------------
// RMSNorm row kernel. X dtype DTX, weight DTW, output always bf16.
// ---------------------------------------------------------------------------
template<int PID, int DTX, int DTW>
__global__ __launch_bounds__(256) void rmsnorm_kernel(
    const int* __restrict__ flag,
    const void* __restrict__ X,
    const void* __restrict__ Wn,
    unsigned short* __restrict__ Out)
{
    if (flag[0] != PID) return;
    const int row = blockIdx.x, t = threadIdx.x;
    float xf[8];
    IO<DTX>::load8(X, (size_t)row * 2048 + t * 8, xf);
    float ss = 0.f;
#pragma unroll
    for (int e = 0; e < 8; e++) ss += xf[e] * xf[e];
#pragma unroll
    for (int off = 32; off; off >>= 1) ss += __shfl_xor(ss, off);
    __shared__ float red[4];
    if ((t & 63) == 0) red[t >> 6] = ss;
    __syncthreads();
    float rr = rsqrtf((red[0] + red[1] + red[2] + red[3]) * (1.0f / 2048.0f) + 1e-6f);
    float wf[8];
    IO<DTW>::load8(Wn, (size_t)t * 8, wf);
    unsigned short ob[8];
#pragma unroll
    for (int e = 0; e < 8; e++) ob[e] = f2b(xf[e] * rr * wf[e]);
    *(uint4*)(Out + (size_t)row * 2048 + t * 8) = *(uint4*)ob;
}

// ---------------------------------------------------------------------------
// GEMM: C(4096,N) = A(4096,K)bf16 @ W(N,ldw)^T [+ Res].  W dtype DTW with
// element offset woff (K- or row-chunking). Res dtype DTR, C dtype DTC.
// 64x64 tile, BK=32, 4 waves x (2x2) mfma_16x16x32_bf16.
// ---------------------------------------------------------------------------
#define GBM 64
#define GBK 32
#define GPAD 8

template<int PID, int DTW, int DTR, int DTC, int EPI>
__global__ __launch_bounds__(256) void gemm_bt(
    const int* __restrict__ flag,
    const unsigned short* __restrict__ A,
    const void* __restrict__ W, size_t woff, int ldw,
    const void* __restrict__ Res,
    void* __restrict__ C,
    int N, int K)
{
    if (flag[0] != PID) return;
    __shared__ unsigned short sA[GBM][GBK + GPAD];
    __shared__ unsigned short sB[GBM][GBK + GPAD];
    const int t = threadIdx.x;
    const int bm = blockIdx.y * GBM, bn = blockIdx.x * GBM;
    const int w = t >> 6, lane = t & 63, quad = lane >> 4, l16 = lane & 15;
    const int wm = (w & 1) * 32, wn = (w >> 1) * 32;
    const int lr = t >> 2;         // 0..63
    const int lc = (t & 3) * 8;    // 0,8,16,24

    f32x4 zero = {0.f, 0.f, 0.f, 0.f};
    f32x4 acc[2][2] = {{zero, zero}, {zero, zero}};

    const unsigned short* Ap = A + (size_t)(bm + lr) * K + lc;
    const size_t wbase = woff + (size_t)(bn + lr) * ldw + lc;

    for (int k0 = 0; k0 < K; k0 += GBK) {
        uint4 av = *(const uint4*)(Ap + k0);
        float wf[8];
        IO<DTW>::load8(W, wbase + k0, wf);
        unsigned short wb[8];
#pragma unroll
        for (int e = 0; e < 8; e++) wb[e] = f2b(wf[e]);
        *(uint4*)&sA[lr][lc] = av;
        *(uint4*)&sB[lr][lc] = *(uint4*)wb;
        __syncthreads();
        bf16x8 af0 = *(const bf16x8*)&sA[wm + l16][quad * 8];
        bf16x8 af1 = *(const bf16x8*)&sA[wm + 16 + l16][quad * 8];
        bf16x8 bf0 = *(const bf16x8*)&sB[wn + l16][quad * 8];
        bf16x8 bf1 = *(const bf16x8*)&sB[wn + 16 + l16][quad * 8];
        acc[0][0] = __builtin_amdgcn_mfma_f32_16x16x32_bf16(af0, bf0, acc[0][0], 0, 0, 0);
        acc[0][1] = __builtin_amdgcn_mfma_f32_16x16x32_bf16(af0, bf1, acc[0][1], 0, 0, 0);
        acc[1][0] = __builtin_amdgcn_mfma_f32_16x16x32_bf16(af1, bf0, acc[1][0], 0, 0, 0);
        acc[1][1] = __builtin_amdgcn_mfma_f32_16x16x32_bf16(af1, bf1, acc[1][1], 0, 0, 0);
        __syncthreads();
    }

#pragma unroll
    for (int mi = 0; mi < 2; mi++)
#pragma unroll
        for (int ni = 0; ni < 2; ni++)
#pragma unroll
            for (int r = 0; r < 4; r++) {
                int row = bm + wm + mi * 16 + quad * 4 + r;
                int col = bn + wn + ni * 16 + l16;
                size_t idx = (size_t)row * N + col;
                float v = acc[mi][ni][r];
                if (EPI == 1) v += IO<DTR>::load1(Res, idx);
                IO<DTC>::store1(C, idx, v);
            }
}

// ---------------------------------------------------------------------------
// Fused gate/up GEMM chunk + SiLU: Out(4096, 4096)bf16 over FF rows
// [woff/2048, +4096). One A tile feeds two B tiles.
// ---------------------------------------------------------------------------
template<int PID, int DTW>
__global__ __launch_bounds__(256) void gemm_gateup_silu(
    const int* __restrict__ flag,
    const unsigned short* __restrict__ A,
    const void* __restrict__ Wg,
    const void* __restrict__ Wu,
    size_t woff,                 // element offset = chunk_row * 2048
    unsigned short* __restrict__ Out,
    int N, int K)
{
    if (flag[0] != PID) return;
    __shared__ unsigned short sA[GBM][GBK + GPAD];
    __shared__ unsigned short sG[GBM][GBK + GPAD];
    __shared__ unsigned short sU[GBM][GBK + GPAD];
    const int t = threadIdx.x;
    const int bm = blockIdx.y * GBM, bn = blockIdx.x * GBM;
    const int w = t >> 6, lane = t & 63, quad = lane >> 4, l16 = lane & 15;
    const int wm = (w & 1) * 32, wn = (w >> 1) * 32;
    const int lr = t >> 2;
    const int lc = (t & 3) * 8;

    f32x4 zero = {0.f, 0.f, 0.f, 0.f};
    f32x4 accg[2][2] = {{zero, zero}, {zero, zero}};
    f32x4 accu[2][2] = {{zero, zero}, {zero, zero}};

    const unsigned short* Ap = A + (size_t)(bm + lr) * K + lc;
    const size_t wbase = woff + (size_t)(bn + lr) * K + lc;

    for (int k0 = 0; k0 < K; k0 += GBK) {
        uint4 av = *(const uint4*)(Ap + k0);
        float gf[8], uf[8];
        IO<DTW>::load8(Wg, wbase + k0, gf);
        IO<DTW>::load8(Wu, wbase + k0, uf);
        unsigned short gb[8], ub[8];
#pragma unroll
        for (int e = 0; e < 8; e++) { gb[e] = f2b(gf[e]); ub[e] = f2b(uf[e]); }
        *(uint4*)&sA[lr][lc] = av;
        *(uint4*)&sG[lr][lc] = *(uint4*)gb;
        *(uint4*)&sU[lr][lc] = *(uint4*)ub;
        __syncthreads();
        bf16x8 af0 = *(const bf16x8*)&sA[wm + l16][quad * 8];
        bf16x8 af1 = *(const bf16x8*)&sA[wm + 16 + l16][quad * 8];
        bf16x8 gf0 = *(const bf16x8*)&sG[wn + l16][quad * 8];
        bf16x8 gf1 = *(const bf16x8*)&sG[wn + 16 + l16][quad * 8];
        bf16x8 uf0 = *(const bf16x8*)&sU[wn + l16][quad * 8];
        bf16x8 uf1 = *(const bf16x8*)&sU[wn + 16 + l16][quad * 8];
        accg[0][0] = __builtin_amdgcn_mfma_f32_16x16x32_bf16(af0, gf0, accg[0][0], 0, 0, 0);
        accg[0][1] = __builtin_amdgcn_mfma_f32_16x16x32_bf16(af0, gf1, accg[0][1], 0, 0, 0);
        accg[1][0] = __builtin_amdgcn_mfma_f32_16x16x32_bf16(af1, gf0, accg[1][0], 0, 0, 0);
        accg[1][1] = __builtin_amdgcn_mfma_f32_16x16x32_bf16(af1, gf1, accg[1][1], 0, 0, 0);
        accu[0][0] = __builtin_amdgcn_mfma_f32_16x16x32_bf16(af0, uf0, accu[0][0], 0, 0, 0);
        accu[0][1] = __builtin_amdgcn_mfma_f32_16x16x32_bf16(af0, uf1, accu[0][1], 0, 0, 0);
        accu[1][0] = __builtin_amdgcn_mfma_f32_16x16x32_bf16(af1, uf0, accu[1][0], 0, 0, 0);
        accu[1][1] = __builtin_amdgcn_mfma_f32_16x16x32_bf16(af1, uf1, accu[1][1], 0, 0, 0);
        __syncthreads();
    }

#pragma unroll
    for (int mi = 0; mi < 2; mi++)
#pragma unroll
        for (int ni = 0; ni < 2; ni++)
#pragma unroll
            for (int r = 0; r < 4; r++) {
                int row = bm + wm + mi * 16 + quad * 4 + r;
                int col = bn + wn + ni * 16 + l16;
                float g = accg[mi][ni][r];
                float s = g / (1.f + __expf(-g));
                Out[(size_t)row * N + col] = f2b(s * accu[mi][ni][r]);
            }
}

// ---------------------------------------------------------------------------
// Attention (bf16 internal only). One block per (b, h, 4 q-rows).
// LDS: S[4][2048] f32, Qs[4][128], LINV[4] => 34848 B dynamic.
// ---------------------------------------------------------------------------
template<int PID>
__global__ __launch_bounds__(256) void attn_kernel(
    const int* __restrict__ flag,
    const unsigned short* __restrict__ QKV,
    unsigned short* __restrict__ O)
{
    if (flag[0] != PID) return;
    extern __shared__ float smem[];
    float* S    = smem;              // 4*2048
    float* Qs   = smem + 4 * 2048;   // 4*128
    float* LINV = Qs + 4 * 128;      // 4

    const int t = threadIdx.x;
    const int idx = blockIdx.x;
    const int qc = idx & 511;
    const int bh = idx >> 9;
    const int b = bh >> 4, hh = bh & 15;
    const int q0 = qc * 4;
    const int ncol = q0 + 4;

    for (int i = t; i < 512; i += 256) {
        int tq = i >> 7, dd = i & 127;
        Qs[i] = b2f(QKV[((size_t)(b * 2048 + q0 + tq)) * 6144 + hh * 128 + dd]);
    }
    __syncthreads();

    const float scale = 0.08838834764831845f;  // 1/sqrt(128)
    for (int j = t; j < ncol; j += 256) {
        const unsigned short* kp = QKV + ((size_t)(b * 2048 + j)) * 6144 + 2048 + hh * 128;
        float acc4[4] = {0.f, 0.f, 0.f, 0.f};
        for (int c = 0; c < 128; c += 8) {
            uint4 kv = *(const uint4*)(kp + c);
            const unsigned short* ku = (const unsigned short*)&kv;
            float kf[8];
#pragma unroll
            for (int e = 0; e < 8; e++) kf[e] = b2f(ku[e]);
#pragma unroll
            for (int tq = 0; tq < 4; tq++) {
                float4 qa = *(const float4*)&Qs[tq * 128 + c];
                float4 qb = *(const float4*)&Qs[tq * 128 + c + 4];
                acc4[tq] += qa.x * kf[0] + qa.y * kf[1] + qa.z * kf[2] + qa.w * kf[3]
                          + qb.x * kf[4] + qb.y * kf[5] + qb.z * kf[6] + qb.w * kf[7];
            }
        }
#pragma unroll
        for (int tq = 0; tq < 4; tq++)
            S[tq * 2048 + j] = (j <= q0 + tq) ? acc4[tq] * scale : -1e30f;
    }
    __syncthreads();

    const int w = t >> 6, lane = t & 63;
    {
        float* sr = S + w * 2048;
        float m = -1e30f;
        for (int j = lane; j < ncol; j += 64) m = fmaxf(m, sr[j]);
#pragma unroll
        for (int off = 32; off; off >>= 1) m = fmaxf(m, __shfl_xor(m, off));
        float sum = 0.f;
        for (int j = lane; j < ncol; j += 64) {
            float p = __expf(sr[j] - m);
            sr[j] = p;
            sum += p;
        }
#pragma unroll
        for (int off = 32; off; off >>= 1) sum += __shfl_xor(sum, off);
        if (lane == 0) LINV[w] = 1.0f / sum;
    }
    __syncthreads();

    const int dd = t & 127, grp = t >> 7;
    float o0 = 0.f, o1 = 0.f;
    const unsigned short* vbase = QKV + ((size_t)(b * 2048)) * 6144 + 4096 + hh * 128 + dd;
    const float* s0 = S + (grp * 2) * 2048;
    const float* s1 = S + (grp * 2 + 1) * 2048;
    for (int j = 0; j < ncol; j++) {
        float vf = b2f(vbase[(size_t)j * 6144]);
        o0 += s0[j] * vf;
        o1 += s1[j] * vf;
    }
    {
        int tq0 = grp * 2;
        O[((size_t)(b * 2048 + q0 + tq0)) * 2048 + hh * 128 + dd] = f2b(o0 * LINV[tq0]);
        O[((size_t)(b * 2048 + q0 + tq0 + 1)) * 2048 + hh * 128 + dd] = f2b(o1 * LINV[tq0 + 1]);
    }
}

// ---------------------------------------------------------------------------
template<int DT>
static void run_pipeline(const void* x, const void* n1w, const void* qkvw,
                         const void* outw, const void* n2w, const void* gatew,
                         const void* upw, const void* downw,
                         void* outp, char* ws, const int* flag, hipStream_t stream)
{
    const size_t MB = 1024 * 1024;
    unsigned short* qkv = (unsigned short*)(ws);            // [0,48)
    unsigned short* x2  = (unsigned short*)(ws);            // [0,16) after qkv dead
    unsigned short* h2  = (unsigned short*)(ws + 16 * MB);  // [16,32)
    unsigned short* a   = (unsigned short*)(ws + 32 * MB);  // [32,64)
    unsigned short* h   = (unsigned short*)(ws + 48 * MB);  // [48,64)
    unsigned short* o   = (unsigned short*)(ws + 48 * MB);  // [48,64) after h dead

    // 1) h = rmsnorm(x, w1)
    rmsnorm_kernel<DT, DT, DT><<<4096, 256, 0, stream>>>(flag, x, n1w, h);
    // 2) qkv = h @ qkv_w^T  (N=6144, K=2048)
    gemm_bt<DT, DT, 1, 1, 0><<<dim3(96, 64), 256, 0, stream>>>(
        flag, h, qkvw, 0, 2048, nullptr, qkv, 6144, 2048);
    // 3) attention -> o
    attn_kernel<DT><<<16384, 256, 34848, stream>>>(flag, qkv, o);
    // 4) x2 = x + o @ out_w^T  (N=2048, K=2048)   [qkv dead]
    gemm_bt<DT, DT, DT, 1, 1><<<dim3(32, 64), 256, 0, stream>>>(
        flag, o, outw, 0, 2048, x, x2, 2048, 2048);
    // 5) h2 = rmsnorm(x2, w2)
    rmsnorm_kernel<DT, 1, DT><<<4096, 256, 0, stream>>>(flag, x2, n2w, h2);
    // 6-9) FF in two chunks of 4096 FF-cols; x2 updated in place with partial.
    // chunk 0
    gemm_gateup_silu<DT, DT><<<dim3(64, 64), 256, 0, stream>>>(
        flag, h2, gatew, upw, (size_t)0, a, 4096, 2048);
    gemm_bt<DT, DT, 1, 1, 1><<<dim3(32, 64), 256, 0, stream>>>(
        flag, a, downw, 0, 8192, x2, x2, 2048, 4096);
    // chunk 1
    gemm_gateup_silu<DT, DT><<<dim3(64, 64), 256, 0, stream>>>(
        flag, h2, gatew, upw, (size_t)4096 * 2048, a, 4096, 2048);
    gemm_bt<DT, DT, 1, DT, 1><<<dim3(32, 64), 256, 0, stream>>>(
        flag, a, downw, 4096, 8192, x2, outp, 2048, 4096);
}

extern "C" void kernel_launch(void* const* d_in, const int* in_sizes, int n_in,
                              void* d_out, int out_size, void* d_ws, size_t ws_size,
                              hipStream_t stream)
{
    const void* x      = d_in[0];
    // d_in[1] = causal mask: implemented analytically, unused
    const void* n1w    = d_in[2];
    const void* qkv_w  = d_in[3];
    const void* out_w  = d_in[4];
    const void* n2w    = d_in[5];
    const void* gate_w = d_in[6];
    const void* up_w   = d_in[7];
    const void* down_w = d_in[8];

    char* ws = (char*)d_ws;
    const size_t MB = 1024 * 1024;
    size_t flag_off = 64 * MB;
    if (ws_size < flag_off + 4) flag_off = (ws_size - 4) & ~(size_t)3;
    int* flag = (int*)(ws + flag_off);

    detect_kernel<<<1, 256, 0, stream>>>((const unsigned int*)x, flag);
    run_pipeline<0>(x, n1w, qkv_w, out_w, n2w, gate_w, up_w, down_w,
                    d_out, ws, flag, stream);
    run_pipeline<1>(x, n1w, qkv_w, out_w, n2w, gate_w, up_w, down_w,
                    d_out, ws, flag, stream);
}